// Round 9
// baseline (138.773 us; speedup 1.0000x reference)
//
#include <hip/hip_runtime.h>
#include <hip/hip_bf16.h>

#define ALPHA 0.2f

typedef __attribute__((ext_vector_type(8))) short short8;
typedef __attribute__((ext_vector_type(4))) short s4;
typedef __attribute__((ext_vector_type(8))) _Float16 h8;
typedef __attribute__((ext_vector_type(2))) _Float16 h2v;
typedef __attribute__((ext_vector_type(4))) float f32x4;
typedef __attribute__((ext_vector_type(2))) short sh2;

static constexpr int B = 4, N = 2048, F = 256, H = 8, D = 32;
static constexpr int SZ_X = B * N * F, SZ_ADJ = B * N * N, SZ_W = H * F * D, SZ_A = H * 2 * D;
static const float C1 = 1.4426950408889634f;           // log2(e)
static const float C2 = ALPHA * 1.4426950408889634f;

// ws layout (bytes):
// 0        WT2  bf16 [kc=8][hd=256][32] 131072   (B-frag-contiguous W)
// 131072   AF   f32  [H][64]            2048
// 133120   S1   f32  [32][2048]         262144
// 395264   UH   f16  [32][2048]         131072
// 526336   VH   f16  [32][2048]         131072
// 657408   WHT  f16  [b][hd=256][2048]  4194304
// 4851712  BM   u64  [B*N*N/64]         2097152   total ~6.6 MB

__device__ __forceinline__ unsigned rne16(unsigned u) {
    return u + 0x7fffu + ((u >> 16) & 1u);
}
__device__ __forceinline__ unsigned pk_rne(float a, float b) {   // bf16 pair
    return __builtin_amdgcn_perm(rne16(__float_as_uint(b)),
                                 rne16(__float_as_uint(a)), 0x07060302u);
}
__device__ __forceinline__ unsigned h2mul(unsigned a, unsigned b) {
    h2v r = __builtin_bit_cast(h2v, a) * __builtin_bit_cast(h2v, b);
    return __builtin_bit_cast(unsigned, r);
}
__device__ __forceinline__ unsigned h2max(unsigned a, unsigned b) {
    h2v r = __builtin_elementwise_max(__builtin_bit_cast(h2v, a),
                                      __builtin_bit_cast(h2v, b));
    return __builtin_bit_cast(unsigned, r);
}
__device__ __forceinline__ unsigned dup16f(float x) {
    unsigned short w = __builtin_bit_cast(unsigned short, (_Float16)x);
    return (unsigned)w | ((unsigned)w << 16);
}
// bits (0,1) of mk -> {0xFFFF,0} half-masks: v_and + v_mul_lo + v_pk_ashrrev_i16
__device__ __forceinline__ unsigned bits2mask(unsigned mk, unsigned mulc) {
    unsigned w = (mk & 3u) * mulc;          // b0 -> bit 15 ; b1 -> bit 31
    sh2 s = __builtin_bit_cast(sh2, w);
    s = s >> 15;                            // smear each 16-bit half from its sign bit
    return __builtin_bit_cast(unsigned, s);
}

// ---- k0: W[h][f][d] -> WT2[f>>5][h*32+d][f&31] bf16; a -> AF --------------
__global__ void k0_prep(const float* __restrict__ Wp, const float* __restrict__ ap,
                        unsigned short* __restrict__ WT2, float* __restrict__ AF) {
    int bid = blockIdx.x;              // 256 = H*D
    int h = bid >> 5, d = bid & 31;
    int f = threadIdx.x;
    unsigned short v = (unsigned short)(rne16(__float_as_uint(Wp[(h * F + f) * D + d])) >> 16);
    WT2[(size_t)(f >> 5) * 8192 + (h * 32 + d) * 32 + (f & 31)] = v;
    if (d == 0 && f < 64) AF[h * 64 + f] = ap[h * 64 + f];
}

// ---- k2: fused {Wh MFMA blocks} + {adj->bitmask blocks}; role by bid%5 ----
__global__ __launch_bounds__(256, 4) void k2_fused(const float* __restrict__ x,
                                                   const unsigned short* __restrict__ WT2,
                                                   const float* __restrict__ AF,
                                                   unsigned short* __restrict__ WHT,
                                                   float* __restrict__ S1,
                                                   _Float16* __restrict__ UH,
                                                   _Float16* __restrict__ VH,
                                                   const int* __restrict__ adj,
                                                   unsigned long long* __restrict__ bm) {
    __shared__ unsigned short XA[16 * 264];   // [n][f] bf16, stride 264 (528B, /16 ok)
    int bid = blockIdx.x;                     // 2560 = 512 mfma + 2048 bitmask, interleaved
    int rr = bid % 5;
    int grp = bid / 5;
    int t = threadIdx.x;

    if (rr != 4) {
        // ---- bitmask role: 32 strips/wave, all 32 loads in flight ----
        int wid = (grp * 4 + rr) * 4 + (t >> 6);   // 8192 wids x 32 strips = 262144
        int lane = t & 63;
        size_t base = (size_t)wid * 32;
        const int* ap2 = adj + base * 64 + lane;
        int v0[16], v1[16];
#pragma unroll
        for (int s = 0; s < 16; s++) v0[s] = ap2[(size_t)s * 64];
#pragma unroll
        for (int s = 0; s < 16; s++) v1[s] = ap2[(size_t)(16 + s) * 64];
        unsigned long long m0[16];
#pragma unroll
        for (int s = 0; s < 16; s++) m0[s] = __ballot(v0[s] != 0);
        unsigned long long m1[16];
#pragma unroll
        for (int s = 0; s < 16; s++) m1[s] = __ballot(v1[s] != 0);
        if (lane == 0) {
#pragma unroll
            for (int s = 0; s < 16; s++) bm[base + s] = m0[s];
#pragma unroll
            for (int s = 0; s < 16; s++) bm[base + 16 + s] = m1[s];
        }
        return;
    }

    // ---- Wh MFMA role ----
    int b = grp >> 7;
    int n0 = (grp & 127) * 16;
    int wave = t >> 6, lane = t & 63;
    int lm = lane & 15, lq = lane >> 4;

    // stage XA coalesced: x fp32 -> bf16
#pragma unroll
    for (int q = 0; q < 4; q++) {
        int idx = q * 256 + t;
        int row = idx >> 6, c16 = idx & 63;
        f32x4 v = *(const f32x4*)(x + (size_t)(b * N + n0 + row) * F + c16 * 4);
        unsigned* dst = (unsigned*)&XA[row * 264 + c16 * 4];
        dst[0] = pk_rne(v[0], v[1]);
        dst[1] = pk_rne(v[2], v[3]);
    }

    // issue kc=0 B-frag loads before the barrier (independent of XA)
    short8 bcur[4], bnext[4];
#pragma unroll
    for (int c = 0; c < 4; c++)
        bcur[c] = *(const short8*)(WT2 + (size_t)(wave * 64 + c * 16 + lm) * 32 + lq * 8);
    __syncthreads();

    f32x4 acc[4] = {};
#pragma unroll
    for (int kc = 0; kc < 8; kc++) {
        if (kc < 7) {
#pragma unroll
            for (int c = 0; c < 4; c++)
                bnext[c] = *(const short8*)(WT2 + (size_t)(kc + 1) * 8192 +
                                            (wave * 64 + c * 16 + lm) * 32 + lq * 8);
        }
        short8 afr = *(const short8*)&XA[lm * 264 + kc * 32 + lq * 8];
#pragma unroll
        for (int c = 0; c < 4; c++)
            acc[c] = __builtin_amdgcn_mfma_f32_16x16x32_bf16(afr, bcur[c], acc[c], 0, 0, 0);
#pragma unroll
        for (int c = 0; c < 4; c++) bcur[c] = bnext[c];
    }

    // epilogue 1: WHT[b][hd][n] f16, 8B packed stores
#pragma unroll
    for (int c = 0; c < 4; c++) {
        int hd = wave * 64 + c * 16 + lm;
        unsigned short w0 = __builtin_bit_cast(unsigned short, (_Float16)acc[c][0]);
        unsigned short w1 = __builtin_bit_cast(unsigned short, (_Float16)acc[c][1]);
        unsigned short w2 = __builtin_bit_cast(unsigned short, (_Float16)acc[c][2]);
        unsigned short w3 = __builtin_bit_cast(unsigned short, (_Float16)acc[c][3]);
        uint2 pk;
        pk.x = (unsigned)w0 | ((unsigned)w1 << 16);
        pk.y = (unsigned)w2 | ((unsigned)w3 << 16);
        *(uint2*)&WHT[((size_t)b * 256 + hd) * 2048 + n0 + lq * 4] = pk;
    }
    // epilogue 2: s1/s2 -> S1/UH/VH
#pragma unroll
    for (int cp = 0; cp < 2; cp++) {
        int h = wave * 2 + cp;
        float a1l = AF[h * 64 + lm],      a1h = AF[h * 64 + 16 + lm];
        float a2l = AF[h * 64 + 32 + lm], a2h = AF[h * 64 + 48 + lm];
#pragma unroll
        for (int r = 0; r < 4; r++) {
            float s1p = acc[cp * 2][r] * a1l + acc[cp * 2 + 1][r] * a1h;
            float s2p = acc[cp * 2][r] * a2l + acc[cp * 2 + 1][r] * a2h;
#pragma unroll
            for (int off = 1; off <= 8; off <<= 1) {
                s1p += __shfl_xor(s1p, off);
                s2p += __shfl_xor(s2p, off);
            }
            if (lm == 0) {
                int bh = b * 8 + h, n = n0 + lq * 4 + r;
                S1[(size_t)bh * 2048 + n] = s1p;
                UH[(size_t)bh * 2048 + n] = (_Float16)exp2f(C1 * s2p);
                VH[(size_t)bh * 2048 + n] = (_Float16)exp2f(C2 * s2p);
            }
        }
    }
}

// ---- k3: 512 thr / 8 waves; j-SPLIT across wave halves --------------------
// waves 0-3 (half=0): rows iw..iw+31, j in [0,1024)  (chunks 0..7,  LW[0..1])
// waves 4-7 (half=1): SAME rows,      j in [1024,2048) (chunks 8..15, LW[2..3])
// Total LDS traffic & staging unchanged vs R8; TLP doubled (16 waves/CU).
// Partials combined via LDS scratch (reuses LW after final barrier).
__global__ __launch_bounds__(512, 4) void k3_attn(
    const unsigned* __restrict__ bm32,
    const unsigned short* __restrict__ WHT,
    const float* __restrict__ S1,
    const _Float16* __restrict__ UH, const _Float16* __restrict__ VH,
    float* __restrict__ out) {
    __shared__ unsigned LM[4][32 * 68];            // per-wsub 32-row bitmask (34816 B)
    __shared__ unsigned short LW[4][32 * 140];     // 2x dbuf [d][128j] (35840 B) + scratch
    __shared__ unsigned LU[1024], LV[1024];        // UH/VH rows for this bh (8192 B)

    // XCD-aware swizzle: group the 16 isup-blocks of one (b,h) on one XCD.
    int bid = blockIdx.x;                          // 512
    int bh = (bid & 7) + ((bid >> 7) << 3);
    int isup = (bid >> 3) & 15;
    int b = bh >> 3, h = bh & 7;
    int i0 = isup * 128;
    int t = threadIdx.x;
    int wave = t >> 6, lane = t & 63;
    int wsub = wave & 3, half = wave >> 2;
    int irow = lane & 15, quad = lane >> 4;
    int iw = i0 + wsub * 32;                       // this wave-pair's 32 i-rows

    // prologue staging: waves 0-3 stage LM[wsub]; waves 4-7 stage LU/LV
    if (half == 0) {
        unsigned* lmp = LM[wsub];
        const unsigned* src = bm32 + ((size_t)(b * N + iw)) * 64;
#pragma unroll 8
        for (int r = 0; r < 32; r++)
            lmp[r * 68 + lane] = src[(size_t)r * 64 + lane];
    } else {
        int u = t - 256;                           // 0..255
        ((uint4*)LU)[u] = ((const uint4*)(UH + (size_t)bh * 2048))[u];
        ((uint4*)LV)[u] = ((const uint4*)(VH + (size_t)bh * 2048))[u];
    }

    const unsigned short* wsrc = WHT + ((size_t)b * 256 + h * 32) * 2048;
    int srow = t >> 4, sseg = (t & 15) * 8;        // staging map: 16B/thread/chunk

    // prologue: stage chunk 0 -> LW[0], chunk 8 -> LW[2]
    {
        const unsigned short* gA = wsrc + (size_t)srow * 2048 + sseg;
        union { short8 v; s4 q[2]; } a0, a1;
        a0.v = *(const short8*)(gA);
        a1.v = *(const short8*)(gA + 8 * 128);
        unsigned short* d0 = &LW[0][srow * 140 + sseg];
        *(s4*)(d0) = a0.q[0]; *(s4*)(d0 + 4) = a0.q[1];
        unsigned short* d1 = &LW[2][srow * 140 + sseg];
        *(s4*)(d1) = a1.q[0]; *(s4*)(d1 + 4) = a1.q[1];
    }

    float s1A = S1[(size_t)bh * 2048 + iw + irow];
    float s1B = S1[(size_t)bh * 2048 + iw + 16 + irow];
    unsigned ci2A = dup16f(exp2f((C2 - C1) * s1A));
    unsigned ci2B = dup16f(exp2f((C2 - C1) * s1B));

    union { h8 v; unsigned u[4]; } ones;
    ones.u[0] = ones.u[1] = ones.u[2] = ones.u[3] = 0x3C003C00u;

    const unsigned MUL = 0x40008000u;              // bit-deposit multiplier (SGPR)

    f32x4 aA0 = {0,0,0,0}, aA1 = {0,0,0,0}, aAL = {0,0,0,0};
    f32x4 aB0 = {0,0,0,0}, aB1 = {0,0,0,0}, aBL = {0,0,0,0};
    __syncthreads();

    for (int g = 0; g < 8; g++) {
        // prefetch next chunk pair (g+1, g+9) into registers
        union { short8 v; s4 q[2]; } pa, pb;
        if (g < 7) {
            const unsigned short* gA = wsrc + (size_t)srow * 2048 + (g + 1) * 128 + sseg;
            pa.v = *(const short8*)(gA);
            pb.v = *(const short8*)(gA + 8 * 128);
        }
        int cc = half * 8 + g;                     // this wave's chunk
        const unsigned short* lwp = LW[half * 2 + (g & 1)];
        const unsigned* lmw = LM[wsub];
        uint4 mkqA = *(const uint4*)&lmw[irow * 68 + cc * 4];
        uint4 mkqB = *(const uint4*)&lmw[(16 + irow) * 68 + cc * 4];
        unsigned mkwA[4] = { mkqA.x, mkqA.y, mkqA.z, mkqA.w };
        unsigned mkwB[4] = { mkqB.x, mkqB.y, mkqB.z, mkqB.w };
#pragma unroll
        for (int hs = 0; hs < 2; hs++) {
            // ---- cluster LDS reads for 2 ks (independent; one wait) ----
            uint4 uws[2], vws[2];
            s4 bf0a[2], bf0b[2], bf1a[2], bf1b[2];
#pragma unroll
            for (int k2 = 0; k2 < 2; k2++) {
                int ks = hs * 2 + k2;
                int jl = ks * 32 + quad * 8;
                uws[k2] = *(const uint4*)&LU[(cc * 128 + jl) >> 1];
                vws[k2] = *(const uint4*)&LV[(cc * 128 + jl) >> 1];
                bf0a[k2] = *(const s4*)&lwp[irow * 140 + jl];
                bf0b[k2] = *(const s4*)&lwp[irow * 140 + jl + 4];
                bf1a[k2] = *(const s4*)&lwp[(16 + irow) * 140 + jl];
                bf1b[k2] = *(const s4*)&lwp[(16 + irow) * 140 + jl + 4];
            }
            // ---- compute: pure VALU + MFMA ----
            __builtin_amdgcn_s_setprio(1);
#pragma unroll
            for (int k2 = 0; k2 < 2; k2++) {
                int ks = hs * 2 + k2;
                unsigned mkA = mkwA[ks] >> (quad * 8);
                unsigned mkB = mkwB[ks] >> (quad * 8);
                unsigned mA0 = bits2mask(mkA,      MUL);
                unsigned mA1 = bits2mask(mkA >> 2, MUL);
                unsigned mA2 = bits2mask(mkA >> 4, MUL);
                unsigned mA3 = bits2mask(mkA >> 6, MUL);
                unsigned mB0 = bits2mask(mkB,      MUL);
                unsigned mB1 = bits2mask(mkB >> 2, MUL);
                unsigned mB2 = bits2mask(mkB >> 4, MUL);
                unsigned mB3 = bits2mask(mkB >> 6, MUL);
                union { h8 v; unsigned u[4]; } afA, afB;
                afA.u[0] = h2max(uws[k2].x, h2mul(ci2A, vws[k2].x)) & mA0;
                afA.u[1] = h2max(uws[k2].y, h2mul(ci2A, vws[k2].y)) & mA1;
                afA.u[2] = h2max(uws[k2].z, h2mul(ci2A, vws[k2].z)) & mA2;
                afA.u[3] = h2max(uws[k2].w, h2mul(ci2A, vws[k2].w)) & mA3;
                afB.u[0] = h2max(uws[k2].x, h2mul(ci2B, vws[k2].x)) & mB0;
                afB.u[1] = h2max(uws[k2].y, h2mul(ci2B, vws[k2].y)) & mB1;
                afB.u[2] = h2max(uws[k2].z, h2mul(ci2B, vws[k2].z)) & mB2;
                afB.u[3] = h2max(uws[k2].w, h2mul(ci2B, vws[k2].w)) & mB3;
                union { short8 v; s4 q[2]; } bf0, bf1;
                bf0.q[0] = bf0a[k2]; bf0.q[1] = bf0b[k2];
                bf1.q[0] = bf1a[k2]; bf1.q[1] = bf1b[k2];
                h8 b0 = __builtin_bit_cast(h8, bf0.v);
                h8 b1 = __builtin_bit_cast(h8, bf1.v);
                aA0 = __builtin_amdgcn_mfma_f32_16x16x32_f16(afA.v, b0, aA0, 0, 0, 0);
                aA1 = __builtin_amdgcn_mfma_f32_16x16x32_f16(afA.v, b1, aA1, 0, 0, 0);
                aAL = __builtin_amdgcn_mfma_f32_16x16x32_f16(afA.v, ones.v, aAL, 0, 0, 0);
                aB0 = __builtin_amdgcn_mfma_f32_16x16x32_f16(afB.v, b0, aB0, 0, 0, 0);
                aB1 = __builtin_amdgcn_mfma_f32_16x16x32_f16(afB.v, b1, aB1, 0, 0, 0);
                aBL = __builtin_amdgcn_mfma_f32_16x16x32_f16(afB.v, ones.v, aBL, 0, 0, 0);
            }
            __builtin_amdgcn_s_setprio(0);
        }
        if (g < 7) {
            // write next pair into buffers last read BEFORE the previous
            // barrier (group0: LW[(g+1)&1]; group1: LW[2+((g+1)&1)]) - safe.
            unsigned short* dA = &LW[(g + 1) & 1][srow * 140 + sseg];
            *(s4*)(dA) = pa.q[0]; *(s4*)(dA + 4) = pa.q[1];
            unsigned short* dB = &LW[2 + ((g + 1) & 1)][srow * 140 + sseg];
            *(s4*)(dB) = pb.q[0]; *(s4*)(dB + 4) = pb.q[1];
        }
        __syncthreads();
    }

    // ---- combine partials: half=1 writes scratch, half=0 adds ----
    f32x4* sp = (f32x4*)&LW[0][0];                 // 6*256*16B = 24576B < 35840B
    int lid = wsub * 64 + lane;                    // 0..255, matches across pair
    if (half == 1) {
        sp[0 * 256 + lid] = aA0;
        sp[1 * 256 + lid] = aA1;
        sp[2 * 256 + lid] = aAL;
        sp[3 * 256 + lid] = aB0;
        sp[4 * 256 + lid] = aB1;
        sp[5 * 256 + lid] = aBL;
    }
    __syncthreads();
    if (half == 1) return;
    aA0 += sp[0 * 256 + lid];
    aA1 += sp[1 * 256 + lid];
    aAL += sp[2 * 256 + lid];
    aB0 += sp[3 * 256 + lid];
    aB1 += sp[4 * 256 + lid];
    aBL += sp[5 * 256 + lid];

#pragma unroll
    for (int r = 0; r < 4; r++) {
        float lA = aAL[r], lB = aBL[r];
        float rA = 1.0f / (lA > 0.f ? lA : 1.f);
        float rB = 1.0f / (lB > 0.f ? lB : 1.f);
        float vA0 = aA0[r] * rA, vA1 = aA1[r] * rA;
        float vB0 = aB0[r] * rB, vB1 = aB1[r] * rB;
        vA0 = vA0 > 0.f ? vA0 : __expf(vA0) - 1.f;   // ELU
        vA1 = vA1 > 0.f ? vA1 : __expf(vA1) - 1.f;
        vB0 = vB0 > 0.f ? vB0 : __expf(vB0) - 1.f;
        vB1 = vB1 > 0.f ? vB1 : __expf(vB1) - 1.f;
        int iA = iw + quad * 4 + r, iB = iA + 16;
        size_t rbA = (size_t)(b * N + iA) * 256 + h * 32;
        size_t rbB = (size_t)(b * N + iB) * 256 + h * 32;
        out[rbA + irow] = vA0;
        out[rbA + 16 + irow] = vA1;
        out[rbB + irow] = vB0;
        out[rbB + 16 + irow] = vB1;
    }
}

extern "C" void kernel_launch(void* const* d_in, const int* in_sizes, int n_in,
                              void* d_out, int out_size, void* d_ws, size_t ws_size,
                              hipStream_t stream) {
    const void *xP = nullptr, *adjP = nullptr, *WP = nullptr, *aP = nullptr;
    for (int i = 0; i < n_in; i++) {
        switch (in_sizes[i]) {
            case SZ_X:   xP = d_in[i]; break;
            case SZ_ADJ: adjP = d_in[i]; break;
            case SZ_W:   WP = d_in[i]; break;
            case SZ_A:   aP = d_in[i]; break;
            default: break;
        }
    }
    if (!xP || !adjP || !WP || !aP) { xP = d_in[0]; adjP = d_in[1]; WP = d_in[2]; aP = d_in[3]; }
    float* out = (float*)d_out;

    char* ws = (char*)d_ws;
    unsigned short* WT2 = (unsigned short*)(ws);
    float* AF  = (float*)(ws + 131072);
    float* S1  = (float*)(ws + 133120);
    _Float16* UH = (_Float16*)(ws + 395264);
    _Float16* VH = (_Float16*)(ws + 526336);
    unsigned short* WHT = (unsigned short*)(ws + 657408);
    unsigned long long* BM = (unsigned long long*)(ws + 4851712);

    k0_prep<<<256, 256, 0, stream>>>((const float*)WP, (const float*)aP, WT2, AF);
    k2_fused<<<2560, 256, 0, stream>>>((const float*)xP, WT2, AF, WHT, S1, UH, VH,
                                       (const int*)adjP, BM);
    k3_attn<<<512, 512, 0, stream>>>((const unsigned*)BM, WHT, S1, UH, VH, out);
}